// Round 12
// baseline (170.832 us; speedup 1.0000x reference)
//
#include <hip/hip_runtime.h>

// SingleVQC via MFMA. R12 vs R10 (best, 55.4us): R11's register-ILP attempt
// spilled (allocator pinned at 64 VGPR; lesson: no new long live ranges).
// R10's loss is phase serialization: 8-wave blocks march through
// VALU(a)->MFMA(b)->VALU+MFMA(c) behind barriers, pipes alternate idle.
// Fix: 256-thread blocks (4 waves, 32 batch rows; wave covers 64 state-cols
// via 4 mg passes; asgn encodes all qubit signs so (d) stays a plain sum).
// ~80 regs/wave, 22KB LDS -> 4 independent blocks/CU interleave phases
// (one block's s-build VALU under another's GEMM MFMA). Grid 1024 blocks.

typedef __attribute__((ext_vector_type(8))) short  bf16x8;
typedef __attribute__((ext_vector_type(4))) float  f32x4;

__device__ __forceinline__ ushort f2bf(float f) {
    unsigned u = __builtin_bit_cast(unsigned, f);
    u += 0x7fffu + ((u >> 16) & 1u);          // RNE
    return (ushort)(u >> 16);
}
__device__ __forceinline__ float bf2f(ushort h) {
    unsigned u = ((unsigned)h) << 16;
    return __builtin_bit_cast(float, u);
}
__device__ __forceinline__ unsigned pack2(float a, float b) {
    return ((unsigned)f2bf(b) << 16) | (unsigned)f2bf(a);
}

// ---------------- gate-table prologue (unchanged, verified) ---------------
__global__ void gate_table_k(const float* __restrict__ theta,
                             float* __restrict__ gt) {
    int idx = blockIdx.x * blockDim.x + threadIdx.x;
    if (idx >= 128) return;
    float phi = theta[idx * 3 + 0];
    float th  = theta[idx * 3 + 1];
    float om  = theta[idx * 3 + 2];
    float ct = __cosf(0.5f * th),         st = __sinf(0.5f * th);
    float ca = __cosf(0.5f * (phi - om)), sa = __sinf(0.5f * (phi - om));
    float cb = __cosf(0.5f * (phi + om)), sb = __sinf(0.5f * (phi + om));
    float* g = gt + idx * 8;
    g[0] =  cb * ct;  g[1] = -sb * ct;
    g[2] = -ca * st;  g[3] = -sa * st;
    g[4] =  ca * st;  g[5] = -sa * st;
    g[6] =  cb * ct;  g[7] =  sb * ct;
}

// ---------------- U-build (unchanged, verified): fragment-major store -----
__global__ void ubuild_k(const float* __restrict__ gt,
                         ushort* __restrict__ Upr, ushort* __restrict__ Upi) {
    const int lane = threadIdx.x & 63;
    const int wid  = threadIdx.x >> 6;
    const int wg   = blockIdx.x * 4 + wid;     // 0..1023
    const int v    = wg >> 8;                  // 0..3
    const int j    = wg & 255;                 // basis column = k index

    float ar[4], ai[4];
#pragma unroll
    for (int r = 0; r < 4; ++r) {
        ar[r] = ((lane * 4 + r) == j) ? 1.0f : 0.0f;
        ai[r] = 0.0f;
    }

#pragma unroll
    for (int l = 0; l < 4; ++l) {
        const float* gl = gt + ((v * 4 + l) * 8) * 8;
#pragma unroll
        for (int q = 0; q < 8; ++q) {
            const float* g = gl + q * 8;
            const float g00r = g[0], g00i = g[1], g01r = g[2], g01i = g[3];
            const float g10r = g[4], g10i = g[5], g11r = g[6], g11i = g[7];
            const int b = 7 - q;
            if (b >= 2) {
                const int xm    = 1 << (b - 2);
                const int mybit = (lane >> (b - 2)) & 1;
                const float cAr = mybit ? g11r : g00r;
                const float cAi = mybit ? g11i : g00i;
                const float cBr = mybit ? g10r : g01r;
                const float cBi = mybit ? g10i : g01i;
#pragma unroll
                for (int r = 0; r < 4; ++r) {
                    const float oR = __shfl_xor(ar[r], xm, 64);
                    const float oI = __shfl_xor(ai[r], xm, 64);
                    const float nR = cAr * ar[r] - cAi * ai[r] + cBr * oR - cBi * oI;
                    const float nI = cAr * ai[r] + cAi * ar[r] + cBr * oI + cBi * oR;
                    ar[r] = nR; ai[r] = nI;
                }
            } else {
                const int step = 1 << b;
#pragma unroll
                for (int r0 = 0; r0 < 4; ++r0) {
                    if ((r0 & step) == 0) {
                        const int r1 = r0 | step;
                        const float a0r = ar[r0], a0i = ai[r0];
                        const float a1r = ar[r1], a1i = ai[r1];
                        ar[r0] = g00r * a0r - g00i * a0i + g01r * a1r - g01i * a1i;
                        ai[r0] = g00r * a0i + g00i * a0r + g01r * a1i + g01i * a1r;
                        ar[r1] = g10r * a0r - g10i * a0i + g11r * a1r - g11i * a1i;
                        ai[r1] = g10r * a0i + g10i * a0r + g11r * a1i + g11i * a1r;
                    }
                }
            }
        }
        const int roff = l + 1;
#pragma unroll
        for (int q = 0; q < 8; ++q) {
            const int t  = (q + roff) & 7;
            const int bc = 7 - q;
            const int bt = 7 - t;
            if (bt >= 2) {
                const int xm = 1 << (bt - 2);
                if (bc >= 2) {
                    const int cbit = (lane >> (bc - 2)) & 1;
#pragma unroll
                    for (int r = 0; r < 4; ++r) {
                        const float oR = __shfl_xor(ar[r], xm, 64);
                        const float oI = __shfl_xor(ai[r], xm, 64);
                        ar[r] = cbit ? oR : ar[r];
                        ai[r] = cbit ? oI : ai[r];
                    }
                } else {
#pragma unroll
                    for (int r = 0; r < 4; ++r) {
                        if ((r >> bc) & 1) {
                            ar[r] = __shfl_xor(ar[r], xm, 64);
                            ai[r] = __shfl_xor(ai[r], xm, 64);
                        }
                    }
                }
            } else {
                const int step = 1 << bt;
                if (bc >= 2) {
                    const int cbit = (lane >> (bc - 2)) & 1;
#pragma unroll
                    for (int r0 = 0; r0 < 4; ++r0) {
                        if (((r0 >> bt) & 1) == 0) {
                            const int r1 = r0 | step;
                            const float t0r = cbit ? ar[r1] : ar[r0];
                            const float t0i = cbit ? ai[r1] : ai[r0];
                            const float t1r = cbit ? ar[r0] : ar[r1];
                            const float t1i = cbit ? ai[r0] : ai[r1];
                            ar[r0] = t0r; ai[r0] = t0i;
                            ar[r1] = t1r; ai[r1] = t1i;
                        }
                    }
                } else {
#pragma unroll
                    for (int r0 = 0; r0 < 4; ++r0) {
                        if (((r0 >> bc) & 1) == 1 && ((r0 >> bt) & 1) == 0) {
                            const int r1 = r0 | step;
                            float tr = ar[r0]; ar[r0] = ar[r1]; ar[r1] = tr;
                            float ti = ai[r0]; ai[r0] = ai[r1]; ai[r1] = ti;
                        }
                    }
                }
            }
        }
    }

    // fragment-major store: Upack[v][ks][g4p][col][e], k = j
    const int ks  = j >> 5;
    const int g4p = (j >> 3) & 3;
    const int e   = j & 7;
    ushort* ur = Upr + (size_t)v * 65536 + ((ks * 4 + g4p) * 256) * 8 + e;
    ushort* ui = Upi + (size_t)v * 65536 + ((ks * 4 + g4p) * 256) * 8 + e;
#pragma unroll
    for (int r = 0; r < 4; ++r) {
        const int col = lane * 4 + r;
        ur[col * 8] = f2bf(ar[r]);
        ui[col * 8] = f2bf(ai[r]);
    }
}

// ---------------- fused main kernel ---------------------------------------
// 1024 blocks x 256 threads; block owns 32 batch rows through all 4 VQCs.
// Wave w (0..3) owns 64 state-cols (w*64..w*64+63) as 4 passes of 16 (mg).
__global__ __launch_bounds__(256, 4)
void vqc_mfma_k(const float* __restrict__ xg,
                const ushort* __restrict__ Upr, const ushort* __restrict__ Upi,
                float* __restrict__ out) {
    __shared__ ushort s_lds[32 * 256];        // 16 KB, XOR-swizzled bf16
    __shared__ float  ex_part[4][32][9];      // 4.5 KB (pad 9)
    __shared__ float  x_lds[32][8];           // 1 KB

    const int tid  = threadIdx.x;
    const int lane = tid & 63;
    const int w    = tid >> 6;       // 0..3: state-cols w*64 .. w*64+63
    const int l15  = lane & 15;
    const int g4   = lane >> 4;
    const int rowbase = blockIdx.x * 32;

    // ---- sign-matrix A fragments, one per mg pass (16 VGPRs total) ----
    // asgn[mg]: A[q=l15][k=g4*8+e], scol = w*64 + mg*16 + g4*4 + (e>>1);
    // value = +-1 (bf16) by bit (7-q) of scol for q<8, else 0. Encodes ALL
    // qubit signs -> (d) is a plain sum.
    bf16x8 asgnA, asgnB, asgnC, asgnD;
    {
        const int q = l15;
#pragma unroll
        for (int mg = 0; mg < 4; ++mg) {
            unsigned wd[4];
#pragma unroll
            for (int p2 = 0; p2 < 4; ++p2) {    // p2 = e>>1
                const int scol = w * 64 + mg * 16 + g4 * 4 + p2;
                ushort uv = 0;
                if (q < 8) uv = ((scol >> (7 - q)) & 1) ? 0xBF80 : 0x3F80;
                wd[p2] = ((unsigned)uv << 16) | uv;   // same sign hi,lo slots
            }
            const uint4 u4 = {wd[0], wd[1], wd[2], wd[3]};
            const bf16x8 f = __builtin_bit_cast(bf16x8, u4);
            if (mg == 0) asgnA = f; else if (mg == 1) asgnB = f;
            else if (mg == 2) asgnC = f; else asgnD = f;
        }
    }

    // initial x into LDS (256 floats, one per thread)
    ((float*)x_lds)[tid] = xg[(size_t)rowbase * 8 + tid];
    __syncthreads();

    const int srow = tid >> 3;     // s-build: 8 threads per row (32 rows)
    const int sc   = tid & 7;      // 32-amp chunk (amp bits 7,6,5 = q0,1,2)

    for (int v = 0; v < 4; ++v) {
        // ---- (a) build s[row][k] = prod_b f_b(k_b), bf16 swizzled ----
        {
            float hc[8], hs[8];
#pragma unroll
            for (int q = 0; q < 8; ++q) {
                float h = 0.5f * x_lds[srow][q];
                hs[q] = __sinf(h); hc[q] = __cosf(h);
            }
            float arr[32];
            arr[0] = (((sc >> 2) & 1) ? hs[0] : hc[0])
                   * (((sc >> 1) & 1) ? hs[1] : hc[1])
                   * (((sc     ) & 1) ? hs[2] : hc[2]);
#define LVL(LEN, FC, FS)                                            \
            _Pragma("unroll")                                       \
            for (int m = (LEN) - 1; m >= 0; --m) {                  \
                arr[2*m+1] = arr[m] * (FS);                         \
                arr[2*m]   = arr[m] * (FC);                         \
            }
            LVL(1,  hc[3], hs[3])   // amp bit4  (q3)
            LVL(2,  hc[4], hs[4])   // bit3      (q4)
            LVL(4,  hc[5], hs[5])   // bit2      (q5)
            LVL(8,  hc[6], hs[6])   // bit1      (q6)
            LVL(16, hc[7], hs[7])   // bit0      (q7)
#undef LVL
            char* sb = (char*)s_lds + srow * 512;
            const int swz = (srow & 7) << 4;
#pragma unroll
            for (int j = 0; j < 4; ++j) {
                uint4 wv;
                wv.x = pack2(arr[j*8+0], arr[j*8+1]);
                wv.y = pack2(arr[j*8+2], arr[j*8+3]);
                wv.z = pack2(arr[j*8+4], arr[j*8+5]);
                wv.w = pack2(arr[j*8+6], arr[j*8+7]);
                *(uint4*)(sb + ((sc * 64 + j * 16) ^ swz)) = wv;
            }
        }
        __syncthreads();

        // ---- (b)+(c): 4 mg passes (16 cols each): GEMM -> p -> E ----
        const ushort* Ur = Upr + (size_t)v * 65536;
        const ushort* Ui = Upi + (size_t)v * 65536;
        f32x4 E0 = {0.f,0.f,0.f,0.f}, E1 = {0.f,0.f,0.f,0.f};

#pragma unroll
        for (int mg = 0; mg < 4; ++mg) {
            f32x4 accr[2], acci[2];
#pragma unroll
            for (int ng = 0; ng < 2; ++ng) {
                accr[ng] = (f32x4){0.f, 0.f, 0.f, 0.f};
                acci[ng] = (f32x4){0.f, 0.f, 0.f, 0.f};
            }
            const int col = w * 64 + mg * 16 + l15;
#pragma unroll
            for (int ks = 0; ks < 8; ++ks) {
                const int boff = ((ks * 4 + g4) * 256 + col) * 8;
                const bf16x8 aur = *(const bf16x8*)(Ur + boff);
                const bf16x8 aui = *(const bf16x8*)(Ui + boff);
                bf16x8 bs[2];
#pragma unroll
                for (int ng = 0; ng < 2; ++ng) {
                    const int row = ng * 16 + l15;
                    const int off = row * 512 +
                        (((ks * 64) + (g4 << 4)) ^ ((row & 7) << 4));
                    bs[ng] = *(const bf16x8*)((const char*)s_lds + off);
                }
#pragma unroll
                for (int ng = 0; ng < 2; ++ng) {
                    accr[ng] = __builtin_amdgcn_mfma_f32_16x16x32_bf16(
                        aur, bs[ng], accr[ng], 0, 0, 0);
                    acci[ng] = __builtin_amdgcn_mfma_f32_16x16x32_bf16(
                        aui, bs[ng], acci[ng], 0, 0, 0);
                }
            }
            // square -> (hi,lo) bf16 packed B-frag -> reduction MFMA into E
            const bf16x8 asgn = (mg == 0) ? asgnA : (mg == 1) ? asgnB
                              : (mg == 2) ? asgnC : asgnD;
#pragma unroll
            for (int ng = 0; ng < 2; ++ng) {
                unsigned wd[4];
#pragma unroll
                for (int r = 0; r < 4; ++r) {
                    const float pr = accr[ng][r] * accr[ng][r]
                                   + acci[ng][r] * acci[ng][r];
                    const ushort hi = f2bf(pr);
                    const ushort lo = f2bf(pr - bf2f(hi));
                    wd[r] = ((unsigned)lo << 16) | hi;
                }
                const uint4 u4 = {wd[0], wd[1], wd[2], wd[3]};
                const bf16x8 pb = __builtin_bit_cast(bf16x8, u4);
                const f32x4 Ein = (ng == 0) ? E0 : E1;
                const f32x4 Eout = __builtin_amdgcn_mfma_f32_16x16x32_bf16(
                    asgn, pb, Ein, 0, 0, 0);
                if (ng == 0) E0 = Eout; else E1 = Eout;
            }
        }

        // ---- write expval partials (q = g4*4+r valid for g4<2) ----
        if (g4 < 2) {
#pragma unroll
            for (int ng = 0; ng < 2; ++ng) {
                const f32x4 Ev = (ng == 0) ? E0 : E1;
                const int row = ng * 16 + l15;   // batch row
#pragma unroll
                for (int r = 0; r < 4; ++r)
                    ex_part[w][row][g4 * 4 + r] = Ev[r];
            }
        }
        __syncthreads();

        // ---- (d) combine col-groups (plain sum; ALL signs in asgn) ----
        {
            const int row = tid >> 3, q = tid & 7;   // 32 rows x 8 q = 256
            float acc = 0.f;
#pragma unroll
            for (int g = 0; g < 4; ++g) acc += ex_part[g][row][q];
            x_lds[row][q] = acc;
        }
        __syncthreads();
    }

    // output = H[:,4] * float(pi - eps_f32)
    const float MULT = 3.14159253589793f;
    if (tid < 32) out[rowbase + tid] = x_lds[tid][4] * MULT;
}

// ---------------- launcher ------------------------------------------------
extern "C" void kernel_launch(void* const* d_in, const int* in_sizes, int n_in,
                              void* d_out, int out_size, void* d_ws, size_t ws_size,
                              hipStream_t stream) {
    const float* x     = (const float*)d_in[0];   // (32768, 8) fp32
    const float* theta = (const float*)d_in[1];   // (4, 4, 8, 3) fp32
    float* out = (float*)d_out;                   // (32768,) fp32

    char*   ws  = (char*)d_ws;
    float*  gt  = (float*)ws;                         // 4 KB
    ushort* Upr = (ushort*)(ws + 4096);               // 512 KB fragment-major
    ushort* Upi = (ushort*)(ws + 4096 + 524288);      // 512 KB

    gate_table_k<<<1, 128, 0, stream>>>(theta, gt);
    ubuild_k<<<256, 256, 0, stream>>>(gt, Upr, Upi);
    vqc_mfma_k<<<1024, 256, 0, stream>>>(x, Upr, Upi, out);
}

// Round 13
// 113.725 us; speedup vs baseline: 1.5021x; 1.5021x over previous
//
#include <hip/hip_runtime.h>

// SingleVQC via MFMA. R13 = R10 main kernel restored VERBATIM (best verified:
// 55.4us steady, 116us bench) + gate_table merged into ubuild (gates computed
// per-block in LDS) to drop one kernel launch + inter-kernel gap (~10-15us of
// the ~60us fixed bench overhead). Lessons encoded from R11/R12 failures:
// (1) blocks must own >=64 batch rows or U restream blows L2 (R12: FETCH
// 17.6->130MB, +55us); (2) allocator pins 64 VGPR -- any added carried
// registers spill (R11: +145MB scratch traffic, +42us).

typedef __attribute__((ext_vector_type(8))) short  bf16x8;
typedef __attribute__((ext_vector_type(4))) float  f32x4;

__device__ __forceinline__ ushort f2bf(float f) {
    unsigned u = __builtin_bit_cast(unsigned, f);
    u += 0x7fffu + ((u >> 16) & 1u);          // RNE
    return (ushort)(u >> 16);
}
__device__ __forceinline__ float bf2f(ushort h) {
    unsigned u = ((unsigned)h) << 16;
    return __builtin_bit_cast(float, u);
}
__device__ __forceinline__ unsigned pack2(float a, float b) {
    return ((unsigned)f2bf(b) << 16) | (unsigned)f2bf(a);
}

// ---------------- U-build with in-block gate table ------------------------
// Gates: 128 = (4 vqc x 4 depth x 8 qubits); each block computes all of them
// into LDS (threads 0..127, ~30 VALU each), then runs the verified shuffle
// sim: one wave per (vqc, basis column). Fragment-major store:
// Upack[v][ks=k>>5][g4p=(k>>3)&3][col][e=k&7], 65536 ushorts per VQC.
__global__ void ubuild_k(const float* __restrict__ theta,
                         ushort* __restrict__ Upr, ushort* __restrict__ Upi) {
    __shared__ float gts[128 * 8];

    {
        const int idx = threadIdx.x;
        if (idx < 128) {
            float phi = theta[idx * 3 + 0];
            float th  = theta[idx * 3 + 1];
            float om  = theta[idx * 3 + 2];
            float ct = __cosf(0.5f * th),         st = __sinf(0.5f * th);
            float ca = __cosf(0.5f * (phi - om)), sa = __sinf(0.5f * (phi - om));
            float cb = __cosf(0.5f * (phi + om)), sb = __sinf(0.5f * (phi + om));
            float* g = gts + idx * 8;
            g[0] =  cb * ct;  g[1] = -sb * ct;
            g[2] = -ca * st;  g[3] = -sa * st;
            g[4] =  ca * st;  g[5] = -sa * st;
            g[6] =  cb * ct;  g[7] =  sb * ct;
        }
    }
    __syncthreads();

    const int lane = threadIdx.x & 63;
    const int wid  = threadIdx.x >> 6;
    const int wg   = blockIdx.x * 4 + wid;     // 0..1023
    const int v    = wg >> 8;                  // 0..3
    const int j    = wg & 255;                 // basis column = k index

    float ar[4], ai[4];
#pragma unroll
    for (int r = 0; r < 4; ++r) {
        ar[r] = ((lane * 4 + r) == j) ? 1.0f : 0.0f;
        ai[r] = 0.0f;
    }

#pragma unroll
    for (int l = 0; l < 4; ++l) {
        const float* gl = gts + ((v * 4 + l) * 8) * 8;
#pragma unroll
        for (int q = 0; q < 8; ++q) {
            const float* g = gl + q * 8;
            const float g00r = g[0], g00i = g[1], g01r = g[2], g01i = g[3];
            const float g10r = g[4], g10i = g[5], g11r = g[6], g11i = g[7];
            const int b = 7 - q;
            if (b >= 2) {
                const int xm    = 1 << (b - 2);
                const int mybit = (lane >> (b - 2)) & 1;
                const float cAr = mybit ? g11r : g00r;
                const float cAi = mybit ? g11i : g00i;
                const float cBr = mybit ? g10r : g01r;
                const float cBi = mybit ? g10i : g01i;
#pragma unroll
                for (int r = 0; r < 4; ++r) {
                    const float oR = __shfl_xor(ar[r], xm, 64);
                    const float oI = __shfl_xor(ai[r], xm, 64);
                    const float nR = cAr * ar[r] - cAi * ai[r] + cBr * oR - cBi * oI;
                    const float nI = cAr * ai[r] + cAi * ar[r] + cBr * oI + cBi * oR;
                    ar[r] = nR; ai[r] = nI;
                }
            } else {
                const int step = 1 << b;
#pragma unroll
                for (int r0 = 0; r0 < 4; ++r0) {
                    if ((r0 & step) == 0) {
                        const int r1 = r0 | step;
                        const float a0r = ar[r0], a0i = ai[r0];
                        const float a1r = ar[r1], a1i = ai[r1];
                        ar[r0] = g00r * a0r - g00i * a0i + g01r * a1r - g01i * a1i;
                        ai[r0] = g00r * a0i + g00i * a0r + g01r * a1i + g01i * a1r;
                        ar[r1] = g10r * a0r - g10i * a0i + g11r * a1r - g11i * a1i;
                        ai[r1] = g10r * a0i + g10i * a0r + g11r * a1i + g11i * a1r;
                    }
                }
            }
        }
        const int roff = l + 1;
#pragma unroll
        for (int q = 0; q < 8; ++q) {
            const int t  = (q + roff) & 7;
            const int bc = 7 - q;
            const int bt = 7 - t;
            if (bt >= 2) {
                const int xm = 1 << (bt - 2);
                if (bc >= 2) {
                    const int cbit = (lane >> (bc - 2)) & 1;
#pragma unroll
                    for (int r = 0; r < 4; ++r) {
                        const float oR = __shfl_xor(ar[r], xm, 64);
                        const float oI = __shfl_xor(ai[r], xm, 64);
                        ar[r] = cbit ? oR : ar[r];
                        ai[r] = cbit ? oI : ai[r];
                    }
                } else {
#pragma unroll
                    for (int r = 0; r < 4; ++r) {
                        if ((r >> bc) & 1) {
                            ar[r] = __shfl_xor(ar[r], xm, 64);
                            ai[r] = __shfl_xor(ai[r], xm, 64);
                        }
                    }
                }
            } else {
                const int step = 1 << bt;
                if (bc >= 2) {
                    const int cbit = (lane >> (bc - 2)) & 1;
#pragma unroll
                    for (int r0 = 0; r0 < 4; ++r0) {
                        if (((r0 >> bt) & 1) == 0) {
                            const int r1 = r0 | step;
                            const float t0r = cbit ? ar[r1] : ar[r0];
                            const float t0i = cbit ? ai[r1] : ai[r0];
                            const float t1r = cbit ? ar[r0] : ar[r1];
                            const float t1i = cbit ? ai[r0] : ai[r1];
                            ar[r0] = t0r; ai[r0] = t0i;
                            ar[r1] = t1r; ai[r1] = t1i;
                        }
                    }
                } else {
#pragma unroll
                    for (int r0 = 0; r0 < 4; ++r0) {
                        if (((r0 >> bc) & 1) == 1 && ((r0 >> bt) & 1) == 0) {
                            const int r1 = r0 | step;
                            float tr = ar[r0]; ar[r0] = ar[r1]; ar[r1] = tr;
                            float ti = ai[r0]; ai[r0] = ai[r1]; ai[r1] = ti;
                        }
                    }
                }
            }
        }
    }

    // fragment-major store: Upack[v][ks][g4p][col][e], k = j
    const int ks  = j >> 5;
    const int g4p = (j >> 3) & 3;
    const int e   = j & 7;
    ushort* ur = Upr + (size_t)v * 65536 + ((ks * 4 + g4p) * 256) * 8 + e;
    ushort* ui = Upi + (size_t)v * 65536 + ((ks * 4 + g4p) * 256) * 8 + e;
#pragma unroll
    for (int r = 0; r < 4; ++r) {
        const int col = lane * 4 + r;
        ur[col * 8] = f2bf(ar[r]);
        ui[col * 8] = f2bf(ai[r]);
    }
}

// ---------------- fused main kernel (R10 VERBATIM) ------------------------
// 512 blocks x 512 threads; block owns 64 batch rows through all 4 VQCs.
// Wave w (0..7) owns 32 state-cols, processed as two 16-col passes (mg).
__global__ __launch_bounds__(512, 4)
void vqc_mfma_k(const float* __restrict__ xg,
                const ushort* __restrict__ Upr, const ushort* __restrict__ Upi,
                float* __restrict__ out) {
    __shared__ ushort s_lds[64 * 256];        // 32 KB, XOR-swizzled bf16
    __shared__ float  ex_part[8][64][9];      // 18 KB (pad 9)
    __shared__ float  x_lds[64][8];           // 2 KB

    const int tid  = threadIdx.x;
    const int lane = tid & 63;
    const int w    = tid >> 6;       // state-col group: cols w*32 .. w*32+31
    const int l15  = lane & 15;
    const int g4   = lane >> 4;
    const int rowbase = blockIdx.x * 64;

    // ---- sign-matrix A fragments (built once; 8 VGPRs) ----
    bf16x8 asgn0, asgn1;
    {
        const int q = l15;
#pragma unroll
        for (int mg = 0; mg < 2; ++mg) {
            unsigned wd[4];
#pragma unroll
            for (int p2 = 0; p2 < 4; ++p2) {    // p2 = e>>1
                const int scol = w * 32 + mg * 16 + g4 * 4 + p2;
                ushort uv = 0;
                if (q < 8) uv = ((scol >> (7 - q)) & 1) ? 0xBF80 : 0x3F80;
                wd[p2] = ((unsigned)uv << 16) | uv;   // same sign hi,lo slots
            }
            const uint4 u4 = {wd[0], wd[1], wd[2], wd[3]};
            if (mg == 0) asgn0 = __builtin_bit_cast(bf16x8, u4);
            else         asgn1 = __builtin_bit_cast(bf16x8, u4);
        }
    }

    // initial x into LDS (512 floats, one per thread)
    ((float*)x_lds)[tid] = xg[(size_t)rowbase * 8 + tid];
    __syncthreads();

    const int srow = tid >> 3;     // s-build: 8 threads per row
    const int sc   = tid & 7;      // 32-amp chunk (amp bits 7,6,5 = q0,1,2)

    for (int v = 0; v < 4; ++v) {
        // ---- (a) build s[row][k] = prod_b f_b(k_b), bf16 swizzled ----
        {
            float hc[8], hs[8];
#pragma unroll
            for (int q = 0; q < 8; ++q) {
                float h = 0.5f * x_lds[srow][q];
                hs[q] = __sinf(h); hc[q] = __cosf(h);
            }
            float arr[32];
            arr[0] = (((sc >> 2) & 1) ? hs[0] : hc[0])
                   * (((sc >> 1) & 1) ? hs[1] : hc[1])
                   * (((sc     ) & 1) ? hs[2] : hc[2]);
#define LVL(LEN, FC, FS)                                            \
            _Pragma("unroll")                                       \
            for (int m = (LEN) - 1; m >= 0; --m) {                  \
                arr[2*m+1] = arr[m] * (FS);                         \
                arr[2*m]   = arr[m] * (FC);                         \
            }
            LVL(1,  hc[3], hs[3])   // amp bit4  (q3)
            LVL(2,  hc[4], hs[4])   // bit3      (q4)
            LVL(4,  hc[5], hs[5])   // bit2      (q5)
            LVL(8,  hc[6], hs[6])   // bit1      (q6)
            LVL(16, hc[7], hs[7])   // bit0      (q7)
#undef LVL
            char* sb = (char*)s_lds + srow * 512;
            const int swz = (srow & 7) << 4;
#pragma unroll
            for (int j = 0; j < 4; ++j) {
                uint4 wv;
                wv.x = pack2(arr[j*8+0], arr[j*8+1]);
                wv.y = pack2(arr[j*8+2], arr[j*8+3]);
                wv.z = pack2(arr[j*8+4], arr[j*8+5]);
                wv.w = pack2(arr[j*8+6], arr[j*8+7]);
                *(uint4*)(sb + ((sc * 64 + j * 16) ^ swz)) = wv;
            }
        }
        __syncthreads();

        // ---- (b)+(c): per mg (16 cols): GEMM (32 AGPR acc) -> p -> E ----
        const ushort* Ur = Upr + (size_t)v * 65536;
        const ushort* Ui = Upi + (size_t)v * 65536;
        f32x4 E0 = {0.f,0.f,0.f,0.f}, E1 = {0.f,0.f,0.f,0.f};
        f32x4 E2 = {0.f,0.f,0.f,0.f}, E3 = {0.f,0.f,0.f,0.f};

#pragma unroll
        for (int mg = 0; mg < 2; ++mg) {
            f32x4 accr[4], acci[4];
#pragma unroll
            for (int ng = 0; ng < 4; ++ng) {
                accr[ng] = (f32x4){0.f, 0.f, 0.f, 0.f};
                acci[ng] = (f32x4){0.f, 0.f, 0.f, 0.f};
            }
            const int col = w * 32 + mg * 16 + l15;
#pragma unroll
            for (int ks = 0; ks < 8; ++ks) {
                const int boff = ((ks * 4 + g4) * 256 + col) * 8;
                const bf16x8 aur = *(const bf16x8*)(Ur + boff);
                const bf16x8 aui = *(const bf16x8*)(Ui + boff);
                bf16x8 bs[4];
#pragma unroll
                for (int ng = 0; ng < 4; ++ng) {
                    const int row = ng * 16 + l15;
                    const int off = row * 512 +
                        (((ks * 64) + (g4 << 4)) ^ ((row & 7) << 4));
                    bs[ng] = *(const bf16x8*)((const char*)s_lds + off);
                }
#pragma unroll
                for (int ng = 0; ng < 4; ++ng) {
                    accr[ng] = __builtin_amdgcn_mfma_f32_16x16x32_bf16(
                        aur, bs[ng], accr[ng], 0, 0, 0);
                    acci[ng] = __builtin_amdgcn_mfma_f32_16x16x32_bf16(
                        aui, bs[ng], acci[ng], 0, 0, 0);
                }
            }
            // square -> (hi,lo) bf16 packed B-frag -> reduction MFMA into E
            const bf16x8 asgn = (mg == 0) ? asgn0 : asgn1;
#pragma unroll
            for (int ng = 0; ng < 4; ++ng) {
                unsigned wd[4];
#pragma unroll
                for (int r = 0; r < 4; ++r) {
                    const float pr = accr[ng][r] * accr[ng][r]
                                   + acci[ng][r] * acci[ng][r];
                    const ushort hi = f2bf(pr);
                    const ushort lo = f2bf(pr - bf2f(hi));
                    wd[r] = ((unsigned)lo << 16) | hi;
                }
                const uint4 u4 = {wd[0], wd[1], wd[2], wd[3]};
                const bf16x8 pb = __builtin_bit_cast(bf16x8, u4);
                f32x4 Ein = (ng == 0) ? E0 : (ng == 1) ? E1 : (ng == 2) ? E2 : E3;
                const f32x4 Eout = __builtin_amdgcn_mfma_f32_16x16x32_bf16(
                    asgn, pb, Ein, 0, 0, 0);
                if (ng == 0) E0 = Eout; else if (ng == 1) E1 = Eout;
                else if (ng == 2) E2 = Eout; else E3 = Eout;
            }
        }

        // ---- write expval partials (q = g4*4+r valid for g4<2) ----
        if (g4 < 2) {
#pragma unroll
            for (int ng = 0; ng < 4; ++ng) {
                const f32x4 Ev = (ng == 0) ? E0 : (ng == 1) ? E1 : (ng == 2) ? E2 : E3;
                const int row = ng * 16 + l15;   // batch row
#pragma unroll
                for (int r = 0; r < 4; ++r)
                    ex_part[w][row][g4 * 4 + r] = Ev[r];
            }
        }
        __syncthreads();

        // ---- (d) combine state-col groups (plain sum; signs in A_sgn) ----
        {
            const int row = tid >> 3, q = tid & 7;
            float acc = 0.f;
#pragma unroll
            for (int g = 0; g < 8; ++g) acc += ex_part[g][row][q];
            x_lds[row][q] = acc;
        }
        __syncthreads();
    }

    // output = H[:,4] * float(pi - eps_f32)
    const float MULT = 3.14159253589793f;
    if (tid < 64) out[rowbase + tid] = x_lds[tid][4] * MULT;
}

// ---------------- launcher ------------------------------------------------
extern "C" void kernel_launch(void* const* d_in, const int* in_sizes, int n_in,
                              void* d_out, int out_size, void* d_ws, size_t ws_size,
                              hipStream_t stream) {
    const float* x     = (const float*)d_in[0];   // (32768, 8) fp32
    const float* theta = (const float*)d_in[1];   // (4, 4, 8, 3) fp32
    float* out = (float*)d_out;                   // (32768,) fp32

    char*   ws  = (char*)d_ws;
    ushort* Upr = (ushort*)(ws + 4096);               // 512 KB fragment-major
    ushort* Upi = (ushort*)(ws + 4096 + 524288);      // 512 KB

    ubuild_k<<<256, 256, 0, stream>>>(theta, Upr, Upi);
    vqc_mfma_k<<<512, 512, 0, stream>>>(x, Upr, Upi, out);
}

// Round 14
// 108.144 us; speedup vs baseline: 1.5797x; 1.0516x over previous
//
#include <hip/hip_runtime.h>

// SingleVQC via MFMA. R14 = R13 (best bench 113.7us; main kernel = R10
// verbatim, merged ubuild) + T5 s_setprio(1/0) around MFMA clusters.
// Rationale: 2 blocks/CU drift through phases -> scheduler can favor the
// MFMA-issuing wave (m191 regime: +4-7%; m190's null was lockstep-only).
// No register/LDS/layout change; numerics bit-identical (absmax 0.046875).

typedef __attribute__((ext_vector_type(8))) short  bf16x8;
typedef __attribute__((ext_vector_type(4))) float  f32x4;

__device__ __forceinline__ ushort f2bf(float f) {
    unsigned u = __builtin_bit_cast(unsigned, f);
    u += 0x7fffu + ((u >> 16) & 1u);          // RNE
    return (ushort)(u >> 16);
}
__device__ __forceinline__ float bf2f(ushort h) {
    unsigned u = ((unsigned)h) << 16;
    return __builtin_bit_cast(float, u);
}
__device__ __forceinline__ unsigned pack2(float a, float b) {
    return ((unsigned)f2bf(b) << 16) | (unsigned)f2bf(a);
}

// ---------------- U-build with in-block gate table (R13, verified) --------
__global__ void ubuild_k(const float* __restrict__ theta,
                         ushort* __restrict__ Upr, ushort* __restrict__ Upi) {
    __shared__ float gts[128 * 8];

    {
        const int idx = threadIdx.x;
        if (idx < 128) {
            float phi = theta[idx * 3 + 0];
            float th  = theta[idx * 3 + 1];
            float om  = theta[idx * 3 + 2];
            float ct = __cosf(0.5f * th),         st = __sinf(0.5f * th);
            float ca = __cosf(0.5f * (phi - om)), sa = __sinf(0.5f * (phi - om));
            float cb = __cosf(0.5f * (phi + om)), sb = __sinf(0.5f * (phi + om));
            float* g = gts + idx * 8;
            g[0] =  cb * ct;  g[1] = -sb * ct;
            g[2] = -ca * st;  g[3] = -sa * st;
            g[4] =  ca * st;  g[5] = -sa * st;
            g[6] =  cb * ct;  g[7] =  sb * ct;
        }
    }
    __syncthreads();

    const int lane = threadIdx.x & 63;
    const int wid  = threadIdx.x >> 6;
    const int wg   = blockIdx.x * 4 + wid;     // 0..1023
    const int v    = wg >> 8;                  // 0..3
    const int j    = wg & 255;                 // basis column = k index

    float ar[4], ai[4];
#pragma unroll
    for (int r = 0; r < 4; ++r) {
        ar[r] = ((lane * 4 + r) == j) ? 1.0f : 0.0f;
        ai[r] = 0.0f;
    }

#pragma unroll
    for (int l = 0; l < 4; ++l) {
        const float* gl = gts + ((v * 4 + l) * 8) * 8;
#pragma unroll
        for (int q = 0; q < 8; ++q) {
            const float* g = gl + q * 8;
            const float g00r = g[0], g00i = g[1], g01r = g[2], g01i = g[3];
            const float g10r = g[4], g10i = g[5], g11r = g[6], g11i = g[7];
            const int b = 7 - q;
            if (b >= 2) {
                const int xm    = 1 << (b - 2);
                const int mybit = (lane >> (b - 2)) & 1;
                const float cAr = mybit ? g11r : g00r;
                const float cAi = mybit ? g11i : g00i;
                const float cBr = mybit ? g10r : g01r;
                const float cBi = mybit ? g10i : g01i;
#pragma unroll
                for (int r = 0; r < 4; ++r) {
                    const float oR = __shfl_xor(ar[r], xm, 64);
                    const float oI = __shfl_xor(ai[r], xm, 64);
                    const float nR = cAr * ar[r] - cAi * ai[r] + cBr * oR - cBi * oI;
                    const float nI = cAr * ai[r] + cAi * ar[r] + cBr * oI + cBi * oR;
                    ar[r] = nR; ai[r] = nI;
                }
            } else {
                const int step = 1 << b;
#pragma unroll
                for (int r0 = 0; r0 < 4; ++r0) {
                    if ((r0 & step) == 0) {
                        const int r1 = r0 | step;
                        const float a0r = ar[r0], a0i = ai[r0];
                        const float a1r = ar[r1], a1i = ai[r1];
                        ar[r0] = g00r * a0r - g00i * a0i + g01r * a1r - g01i * a1i;
                        ai[r0] = g00r * a0i + g00i * a0r + g01r * a1i + g01i * a1r;
                        ar[r1] = g10r * a0r - g10i * a0i + g11r * a1r - g11i * a1i;
                        ai[r1] = g10r * a0i + g10i * a0r + g11r * a1i + g11i * a1r;
                    }
                }
            }
        }
        const int roff = l + 1;
#pragma unroll
        for (int q = 0; q < 8; ++q) {
            const int t  = (q + roff) & 7;
            const int bc = 7 - q;
            const int bt = 7 - t;
            if (bt >= 2) {
                const int xm = 1 << (bt - 2);
                if (bc >= 2) {
                    const int cbit = (lane >> (bc - 2)) & 1;
#pragma unroll
                    for (int r = 0; r < 4; ++r) {
                        const float oR = __shfl_xor(ar[r], xm, 64);
                        const float oI = __shfl_xor(ai[r], xm, 64);
                        ar[r] = cbit ? oR : ar[r];
                        ai[r] = cbit ? oI : ai[r];
                    }
                } else {
#pragma unroll
                    for (int r = 0; r < 4; ++r) {
                        if ((r >> bc) & 1) {
                            ar[r] = __shfl_xor(ar[r], xm, 64);
                            ai[r] = __shfl_xor(ai[r], xm, 64);
                        }
                    }
                }
            } else {
                const int step = 1 << bt;
                if (bc >= 2) {
                    const int cbit = (lane >> (bc - 2)) & 1;
#pragma unroll
                    for (int r0 = 0; r0 < 4; ++r0) {
                        if (((r0 >> bt) & 1) == 0) {
                            const int r1 = r0 | step;
                            const float t0r = cbit ? ar[r1] : ar[r0];
                            const float t0i = cbit ? ai[r1] : ai[r0];
                            const float t1r = cbit ? ar[r0] : ar[r1];
                            const float t1i = cbit ? ai[r0] : ai[r1];
                            ar[r0] = t0r; ai[r0] = t0i;
                            ar[r1] = t1r; ai[r1] = t1i;
                        }
                    }
                } else {
#pragma unroll
                    for (int r0 = 0; r0 < 4; ++r0) {
                        if (((r0 >> bc) & 1) == 1 && ((r0 >> bt) & 1) == 0) {
                            const int r1 = r0 | step;
                            float tr = ar[r0]; ar[r0] = ar[r1]; ar[r1] = tr;
                            float ti = ai[r0]; ai[r0] = ai[r1]; ai[r1] = ti;
                        }
                    }
                }
            }
        }
    }

    // fragment-major store: Upack[v][ks][g4p][col][e], k = j
    const int ks  = j >> 5;
    const int g4p = (j >> 3) & 3;
    const int e   = j & 7;
    ushort* ur = Upr + (size_t)v * 65536 + ((ks * 4 + g4p) * 256) * 8 + e;
    ushort* ui = Upi + (size_t)v * 65536 + ((ks * 4 + g4p) * 256) * 8 + e;
#pragma unroll
    for (int r = 0; r < 4; ++r) {
        const int col = lane * 4 + r;
        ur[col * 8] = f2bf(ar[r]);
        ui[col * 8] = f2bf(ai[r]);
    }
}

// ---------------- fused main kernel (R10 + setprio) -----------------------
// 512 blocks x 512 threads; block owns 64 batch rows through all 4 VQCs.
// Wave w (0..7) owns 32 state-cols, processed as two 16-col passes (mg).
__global__ __launch_bounds__(512, 4)
void vqc_mfma_k(const float* __restrict__ xg,
                const ushort* __restrict__ Upr, const ushort* __restrict__ Upi,
                float* __restrict__ out) {
    __shared__ ushort s_lds[64 * 256];        // 32 KB, XOR-swizzled bf16
    __shared__ float  ex_part[8][64][9];      // 18 KB (pad 9)
    __shared__ float  x_lds[64][8];           // 2 KB

    const int tid  = threadIdx.x;
    const int lane = tid & 63;
    const int w    = tid >> 6;       // state-col group: cols w*32 .. w*32+31
    const int l15  = lane & 15;
    const int g4   = lane >> 4;
    const int rowbase = blockIdx.x * 64;

    // ---- sign-matrix A fragments (built once; 8 VGPRs) ----
    bf16x8 asgn0, asgn1;
    {
        const int q = l15;
#pragma unroll
        for (int mg = 0; mg < 2; ++mg) {
            unsigned wd[4];
#pragma unroll
            for (int p2 = 0; p2 < 4; ++p2) {    // p2 = e>>1
                const int scol = w * 32 + mg * 16 + g4 * 4 + p2;
                ushort uv = 0;
                if (q < 8) uv = ((scol >> (7 - q)) & 1) ? 0xBF80 : 0x3F80;
                wd[p2] = ((unsigned)uv << 16) | uv;   // same sign hi,lo slots
            }
            const uint4 u4 = {wd[0], wd[1], wd[2], wd[3]};
            if (mg == 0) asgn0 = __builtin_bit_cast(bf16x8, u4);
            else         asgn1 = __builtin_bit_cast(bf16x8, u4);
        }
    }

    // initial x into LDS (512 floats, one per thread)
    ((float*)x_lds)[tid] = xg[(size_t)rowbase * 8 + tid];
    __syncthreads();

    const int srow = tid >> 3;     // s-build: 8 threads per row
    const int sc   = tid & 7;      // 32-amp chunk (amp bits 7,6,5 = q0,1,2)

    for (int v = 0; v < 4; ++v) {
        // ---- (a) build s[row][k] = prod_b f_b(k_b), bf16 swizzled ----
        {
            float hc[8], hs[8];
#pragma unroll
            for (int q = 0; q < 8; ++q) {
                float h = 0.5f * x_lds[srow][q];
                hs[q] = __sinf(h); hc[q] = __cosf(h);
            }
            float arr[32];
            arr[0] = (((sc >> 2) & 1) ? hs[0] : hc[0])
                   * (((sc >> 1) & 1) ? hs[1] : hc[1])
                   * (((sc     ) & 1) ? hs[2] : hc[2]);
#define LVL(LEN, FC, FS)                                            \
            _Pragma("unroll")                                       \
            for (int m = (LEN) - 1; m >= 0; --m) {                  \
                arr[2*m+1] = arr[m] * (FS);                         \
                arr[2*m]   = arr[m] * (FC);                         \
            }
            LVL(1,  hc[3], hs[3])   // amp bit4  (q3)
            LVL(2,  hc[4], hs[4])   // bit3      (q4)
            LVL(4,  hc[5], hs[5])   // bit2      (q5)
            LVL(8,  hc[6], hs[6])   // bit1      (q6)
            LVL(16, hc[7], hs[7])   // bit0      (q7)
#undef LVL
            char* sb = (char*)s_lds + srow * 512;
            const int swz = (srow & 7) << 4;
#pragma unroll
            for (int j = 0; j < 4; ++j) {
                uint4 wv;
                wv.x = pack2(arr[j*8+0], arr[j*8+1]);
                wv.y = pack2(arr[j*8+2], arr[j*8+3]);
                wv.z = pack2(arr[j*8+4], arr[j*8+5]);
                wv.w = pack2(arr[j*8+6], arr[j*8+7]);
                *(uint4*)(sb + ((sc * 64 + j * 16) ^ swz)) = wv;
            }
        }
        __syncthreads();

        // ---- (b)+(c): per mg (16 cols): GEMM (32 AGPR acc) -> p -> E ----
        const ushort* Ur = Upr + (size_t)v * 65536;
        const ushort* Ui = Upi + (size_t)v * 65536;
        f32x4 E0 = {0.f,0.f,0.f,0.f}, E1 = {0.f,0.f,0.f,0.f};
        f32x4 E2 = {0.f,0.f,0.f,0.f}, E3 = {0.f,0.f,0.f,0.f};

#pragma unroll
        for (int mg = 0; mg < 2; ++mg) {
            f32x4 accr[4], acci[4];
#pragma unroll
            for (int ng = 0; ng < 4; ++ng) {
                accr[ng] = (f32x4){0.f, 0.f, 0.f, 0.f};
                acci[ng] = (f32x4){0.f, 0.f, 0.f, 0.f};
            }
            const int col = w * 32 + mg * 16 + l15;
#pragma unroll
            for (int ks = 0; ks < 8; ++ks) {
                const int boff = ((ks * 4 + g4) * 256 + col) * 8;
                const bf16x8 aur = *(const bf16x8*)(Ur + boff);
                const bf16x8 aui = *(const bf16x8*)(Ui + boff);
                bf16x8 bs[4];
#pragma unroll
                for (int ng = 0; ng < 4; ++ng) {
                    const int row = ng * 16 + l15;
                    const int off = row * 512 +
                        (((ks * 64) + (g4 << 4)) ^ ((row & 7) << 4));
                    bs[ng] = *(const bf16x8*)((const char*)s_lds + off);
                }
                __builtin_amdgcn_s_setprio(1);        // T5: favor MFMA wave
#pragma unroll
                for (int ng = 0; ng < 4; ++ng) {
                    accr[ng] = __builtin_amdgcn_mfma_f32_16x16x32_bf16(
                        aur, bs[ng], accr[ng], 0, 0, 0);
                    acci[ng] = __builtin_amdgcn_mfma_f32_16x16x32_bf16(
                        aui, bs[ng], acci[ng], 0, 0, 0);
                }
                __builtin_amdgcn_s_setprio(0);
            }
            // square -> (hi,lo) bf16 packed B-frag -> reduction MFMA into E
            const bf16x8 asgn = (mg == 0) ? asgn0 : asgn1;
#pragma unroll
            for (int ng = 0; ng < 4; ++ng) {
                unsigned wd[4];
#pragma unroll
                for (int r = 0; r < 4; ++r) {
                    const float pr = accr[ng][r] * accr[ng][r]
                                   + acci[ng][r] * acci[ng][r];
                    const ushort hi = f2bf(pr);
                    const ushort lo = f2bf(pr - bf2f(hi));
                    wd[r] = ((unsigned)lo << 16) | hi;
                }
                const uint4 u4 = {wd[0], wd[1], wd[2], wd[3]};
                const bf16x8 pb = __builtin_bit_cast(bf16x8, u4);
                f32x4 Ein = (ng == 0) ? E0 : (ng == 1) ? E1 : (ng == 2) ? E2 : E3;
                __builtin_amdgcn_s_setprio(1);
                const f32x4 Eout = __builtin_amdgcn_mfma_f32_16x16x32_bf16(
                    asgn, pb, Ein, 0, 0, 0);
                __builtin_amdgcn_s_setprio(0);
                if (ng == 0) E0 = Eout; else if (ng == 1) E1 = Eout;
                else if (ng == 2) E2 = Eout; else E3 = Eout;
            }
        }

        // ---- write expval partials (q = g4*4+r valid for g4<2) ----
        if (g4 < 2) {
#pragma unroll
            for (int ng = 0; ng < 4; ++ng) {
                const f32x4 Ev = (ng == 0) ? E0 : (ng == 1) ? E1 : (ng == 2) ? E2 : E3;
                const int row = ng * 16 + l15;   // batch row
#pragma unroll
                for (int r = 0; r < 4; ++r)
                    ex_part[w][row][g4 * 4 + r] = Ev[r];
            }
        }
        __syncthreads();

        // ---- (d) combine state-col groups (plain sum; signs in A_sgn) ----
        {
            const int row = tid >> 3, q = tid & 7;
            float acc = 0.f;
#pragma unroll
            for (int g = 0; g < 8; ++g) acc += ex_part[g][row][q];
            x_lds[row][q] = acc;
        }
        __syncthreads();
    }

    // output = H[:,4] * float(pi - eps_f32)
    const float MULT = 3.14159253589793f;
    if (tid < 64) out[rowbase + tid] = x_lds[tid][4] * MULT;
}

// ---------------- launcher ------------------------------------------------
extern "C" void kernel_launch(void* const* d_in, const int* in_sizes, int n_in,
                              void* d_out, int out_size, void* d_ws, size_t ws_size,
                              hipStream_t stream) {
    const float* x     = (const float*)d_in[0];   // (32768, 8) fp32
    const float* theta = (const float*)d_in[1];   // (4, 4, 8, 3) fp32
    float* out = (float*)d_out;                   // (32768,) fp32

    char*   ws  = (char*)d_ws;
    ushort* Upr = (ushort*)(ws + 4096);               // 512 KB fragment-major
    ushort* Upi = (ushort*)(ws + 4096 + 524288);      // 512 KB

    ubuild_k<<<256, 256, 0, stream>>>(theta, Upr, Upi);
    vqc_mfma_k<<<512, 512, 0, stream>>>(x, Upr, Upi, out);
}

// Round 15
// 105.915 us; speedup vs baseline: 1.6129x; 1.0210x over previous
//
#include <hip/hip_runtime.h>

// SingleVQC via MFMA. R15 = R14 (best: 50.5us steady, 108us bench) with the
// software bf16 packing replaced by gfx950's v_cvt_pk_bf16_f32 (T12 recipe):
// s-build pack2 (9 int-ops) -> 1 cvt_pk; (c) hi/lo split (13 ops) -> 4 ops
// (cvt_pk, shl, sub, cvt_pk). ~45% of per-thread VALU deleted; numerics RNE
// -> absmax expected ~0.046875 unchanged. Everything else identical to R14.

typedef __attribute__((ext_vector_type(8))) short  bf16x8;
typedef __attribute__((ext_vector_type(4))) float  f32x4;

__device__ __forceinline__ ushort f2bf(float f) {
    unsigned u = __builtin_bit_cast(unsigned, f);
    u += 0x7fffu + ((u >> 16) & 1u);          // RNE
    return (ushort)(u >> 16);
}
// HW packed conversion: low16 = bf16(a), high16 = bf16(b), RNE.
__device__ __forceinline__ unsigned cvtpk(float a, float b) {
    unsigned r;
    asm("v_cvt_pk_bf16_f32 %0, %1, %2" : "=v"(r) : "v"(a), "v"(b));
    return r;
}

// ---------------- U-build with in-block gate table (R13, verified) --------
__global__ void ubuild_k(const float* __restrict__ theta,
                         ushort* __restrict__ Upr, ushort* __restrict__ Upi) {
    __shared__ float gts[128 * 8];

    {
        const int idx = threadIdx.x;
        if (idx < 128) {
            float phi = theta[idx * 3 + 0];
            float th  = theta[idx * 3 + 1];
            float om  = theta[idx * 3 + 2];
            float ct = __cosf(0.5f * th),         st = __sinf(0.5f * th);
            float ca = __cosf(0.5f * (phi - om)), sa = __sinf(0.5f * (phi - om));
            float cb = __cosf(0.5f * (phi + om)), sb = __sinf(0.5f * (phi + om));
            float* g = gts + idx * 8;
            g[0] =  cb * ct;  g[1] = -sb * ct;
            g[2] = -ca * st;  g[3] = -sa * st;
            g[4] =  ca * st;  g[5] = -sa * st;
            g[6] =  cb * ct;  g[7] =  sb * ct;
        }
    }
    __syncthreads();

    const int lane = threadIdx.x & 63;
    const int wid  = threadIdx.x >> 6;
    const int wg   = blockIdx.x * 4 + wid;     // 0..1023
    const int v    = wg >> 8;                  // 0..3
    const int j    = wg & 255;                 // basis column = k index

    float ar[4], ai[4];
#pragma unroll
    for (int r = 0; r < 4; ++r) {
        ar[r] = ((lane * 4 + r) == j) ? 1.0f : 0.0f;
        ai[r] = 0.0f;
    }

#pragma unroll
    for (int l = 0; l < 4; ++l) {
        const float* gl = gts + ((v * 4 + l) * 8) * 8;
#pragma unroll
        for (int q = 0; q < 8; ++q) {
            const float* g = gl + q * 8;
            const float g00r = g[0], g00i = g[1], g01r = g[2], g01i = g[3];
            const float g10r = g[4], g10i = g[5], g11r = g[6], g11i = g[7];
            const int b = 7 - q;
            if (b >= 2) {
                const int xm    = 1 << (b - 2);
                const int mybit = (lane >> (b - 2)) & 1;
                const float cAr = mybit ? g11r : g00r;
                const float cAi = mybit ? g11i : g00i;
                const float cBr = mybit ? g10r : g01r;
                const float cBi = mybit ? g10i : g01i;
#pragma unroll
                for (int r = 0; r < 4; ++r) {
                    const float oR = __shfl_xor(ar[r], xm, 64);
                    const float oI = __shfl_xor(ai[r], xm, 64);
                    const float nR = cAr * ar[r] - cAi * ai[r] + cBr * oR - cBi * oI;
                    const float nI = cAr * ai[r] + cAi * ar[r] + cBr * oI + cBi * oR;
                    ar[r] = nR; ai[r] = nI;
                }
            } else {
                const int step = 1 << b;
#pragma unroll
                for (int r0 = 0; r0 < 4; ++r0) {
                    if ((r0 & step) == 0) {
                        const int r1 = r0 | step;
                        const float a0r = ar[r0], a0i = ai[r0];
                        const float a1r = ar[r1], a1i = ai[r1];
                        ar[r0] = g00r * a0r - g00i * a0i + g01r * a1r - g01i * a1i;
                        ai[r0] = g00r * a0i + g00i * a0r + g01r * a1i + g01i * a1r;
                        ar[r1] = g10r * a0r - g10i * a0i + g11r * a1r - g11i * a1i;
                        ai[r1] = g10r * a0i + g10i * a0r + g11r * a1i + g11i * a1r;
                    }
                }
            }
        }
        const int roff = l + 1;
#pragma unroll
        for (int q = 0; q < 8; ++q) {
            const int t  = (q + roff) & 7;
            const int bc = 7 - q;
            const int bt = 7 - t;
            if (bt >= 2) {
                const int xm = 1 << (bt - 2);
                if (bc >= 2) {
                    const int cbit = (lane >> (bc - 2)) & 1;
#pragma unroll
                    for (int r = 0; r < 4; ++r) {
                        const float oR = __shfl_xor(ar[r], xm, 64);
                        const float oI = __shfl_xor(ai[r], xm, 64);
                        ar[r] = cbit ? oR : ar[r];
                        ai[r] = cbit ? oI : ai[r];
                    }
                } else {
#pragma unroll
                    for (int r = 0; r < 4; ++r) {
                        if ((r >> bc) & 1) {
                            ar[r] = __shfl_xor(ar[r], xm, 64);
                            ai[r] = __shfl_xor(ai[r], xm, 64);
                        }
                    }
                }
            } else {
                const int step = 1 << bt;
                if (bc >= 2) {
                    const int cbit = (lane >> (bc - 2)) & 1;
#pragma unroll
                    for (int r0 = 0; r0 < 4; ++r0) {
                        if (((r0 >> bt) & 1) == 0) {
                            const int r1 = r0 | step;
                            const float t0r = cbit ? ar[r1] : ar[r0];
                            const float t0i = cbit ? ai[r1] : ai[r0];
                            const float t1r = cbit ? ar[r0] : ar[r1];
                            const float t1i = cbit ? ai[r0] : ai[r1];
                            ar[r0] = t0r; ai[r0] = t0i;
                            ar[r1] = t1r; ai[r1] = t1i;
                        }
                    }
                } else {
#pragma unroll
                    for (int r0 = 0; r0 < 4; ++r0) {
                        if (((r0 >> bc) & 1) == 1 && ((r0 >> bt) & 1) == 0) {
                            const int r1 = r0 | step;
                            float tr = ar[r0]; ar[r0] = ar[r1]; ar[r1] = tr;
                            float ti = ai[r0]; ai[r0] = ai[r1]; ai[r1] = ti;
                        }
                    }
                }
            }
        }
    }

    // fragment-major store: Upack[v][ks][g4p][col][e], k = j
    const int ks  = j >> 5;
    const int g4p = (j >> 3) & 3;
    const int e   = j & 7;
    ushort* ur = Upr + (size_t)v * 65536 + ((ks * 4 + g4p) * 256) * 8 + e;
    ushort* ui = Upi + (size_t)v * 65536 + ((ks * 4 + g4p) * 256) * 8 + e;
#pragma unroll
    for (int r = 0; r < 4; ++r) {
        const int col = lane * 4 + r;
        ur[col * 8] = f2bf(ar[r]);
        ui[col * 8] = f2bf(ai[r]);
    }
}

// ---------------- fused main kernel (R14 + cvt_pk) ------------------------
// 512 blocks x 512 threads; block owns 64 batch rows through all 4 VQCs.
// Wave w (0..7) owns 32 state-cols, processed as two 16-col passes (mg).
__global__ __launch_bounds__(512, 4)
void vqc_mfma_k(const float* __restrict__ xg,
                const ushort* __restrict__ Upr, const ushort* __restrict__ Upi,
                float* __restrict__ out) {
    __shared__ ushort s_lds[64 * 256];        // 32 KB, XOR-swizzled bf16
    __shared__ float  ex_part[8][64][9];      // 18 KB (pad 9)
    __shared__ float  x_lds[64][8];           // 2 KB

    const int tid  = threadIdx.x;
    const int lane = tid & 63;
    const int w    = tid >> 6;       // state-col group: cols w*32 .. w*32+31
    const int l15  = lane & 15;
    const int g4   = lane >> 4;
    const int rowbase = blockIdx.x * 64;

    // ---- sign-matrix A fragments (built once; 8 VGPRs) ----
    bf16x8 asgn0, asgn1;
    {
        const int q = l15;
#pragma unroll
        for (int mg = 0; mg < 2; ++mg) {
            unsigned wd[4];
#pragma unroll
            for (int p2 = 0; p2 < 4; ++p2) {    // p2 = e>>1
                const int scol = w * 32 + mg * 16 + g4 * 4 + p2;
                ushort uv = 0;
                if (q < 8) uv = ((scol >> (7 - q)) & 1) ? 0xBF80 : 0x3F80;
                wd[p2] = ((unsigned)uv << 16) | uv;   // same sign hi,lo slots
            }
            const uint4 u4 = {wd[0], wd[1], wd[2], wd[3]};
            if (mg == 0) asgn0 = __builtin_bit_cast(bf16x8, u4);
            else         asgn1 = __builtin_bit_cast(bf16x8, u4);
        }
    }

    // initial x into LDS (512 floats, one per thread)
    ((float*)x_lds)[tid] = xg[(size_t)rowbase * 8 + tid];
    __syncthreads();

    const int srow = tid >> 3;     // s-build: 8 threads per row
    const int sc   = tid & 7;      // 32-amp chunk (amp bits 7,6,5 = q0,1,2)

    for (int v = 0; v < 4; ++v) {
        // ---- (a) build s[row][k] = prod_b f_b(k_b), bf16 swizzled ----
        {
            float hc[8], hs[8];
#pragma unroll
            for (int q = 0; q < 8; ++q) {
                float h = 0.5f * x_lds[srow][q];
                hs[q] = __sinf(h); hc[q] = __cosf(h);
            }
            float arr[32];
            arr[0] = (((sc >> 2) & 1) ? hs[0] : hc[0])
                   * (((sc >> 1) & 1) ? hs[1] : hc[1])
                   * (((sc     ) & 1) ? hs[2] : hc[2]);
#define LVL(LEN, FC, FS)                                            \
            _Pragma("unroll")                                       \
            for (int m = (LEN) - 1; m >= 0; --m) {                  \
                arr[2*m+1] = arr[m] * (FS);                         \
                arr[2*m]   = arr[m] * (FC);                         \
            }
            LVL(1,  hc[3], hs[3])   // amp bit4  (q3)
            LVL(2,  hc[4], hs[4])   // bit3      (q4)
            LVL(4,  hc[5], hs[5])   // bit2      (q5)
            LVL(8,  hc[6], hs[6])   // bit1      (q6)
            LVL(16, hc[7], hs[7])   // bit0      (q7)
#undef LVL
            char* sb = (char*)s_lds + srow * 512;
            const int swz = (srow & 7) << 4;
#pragma unroll
            for (int j = 0; j < 4; ++j) {
                uint4 wv;
                wv.x = cvtpk(arr[j*8+0], arr[j*8+1]);
                wv.y = cvtpk(arr[j*8+2], arr[j*8+3]);
                wv.z = cvtpk(arr[j*8+4], arr[j*8+5]);
                wv.w = cvtpk(arr[j*8+6], arr[j*8+7]);
                *(uint4*)(sb + ((sc * 64 + j * 16) ^ swz)) = wv;
            }
        }
        __syncthreads();

        // ---- (b)+(c): per mg (16 cols): GEMM (32 AGPR acc) -> p -> E ----
        const ushort* Ur = Upr + (size_t)v * 65536;
        const ushort* Ui = Upi + (size_t)v * 65536;
        f32x4 E0 = {0.f,0.f,0.f,0.f}, E1 = {0.f,0.f,0.f,0.f};
        f32x4 E2 = {0.f,0.f,0.f,0.f}, E3 = {0.f,0.f,0.f,0.f};

#pragma unroll
        for (int mg = 0; mg < 2; ++mg) {
            f32x4 accr[4], acci[4];
#pragma unroll
            for (int ng = 0; ng < 4; ++ng) {
                accr[ng] = (f32x4){0.f, 0.f, 0.f, 0.f};
                acci[ng] = (f32x4){0.f, 0.f, 0.f, 0.f};
            }
            const int col = w * 32 + mg * 16 + l15;
#pragma unroll
            for (int ks = 0; ks < 8; ++ks) {
                const int boff = ((ks * 4 + g4) * 256 + col) * 8;
                const bf16x8 aur = *(const bf16x8*)(Ur + boff);
                const bf16x8 aui = *(const bf16x8*)(Ui + boff);
                bf16x8 bs[4];
#pragma unroll
                for (int ng = 0; ng < 4; ++ng) {
                    const int row = ng * 16 + l15;
                    const int off = row * 512 +
                        (((ks * 64) + (g4 << 4)) ^ ((row & 7) << 4));
                    bs[ng] = *(const bf16x8*)((const char*)s_lds + off);
                }
                __builtin_amdgcn_s_setprio(1);        // T5: favor MFMA wave
#pragma unroll
                for (int ng = 0; ng < 4; ++ng) {
                    accr[ng] = __builtin_amdgcn_mfma_f32_16x16x32_bf16(
                        aur, bs[ng], accr[ng], 0, 0, 0);
                    acci[ng] = __builtin_amdgcn_mfma_f32_16x16x32_bf16(
                        aui, bs[ng], acci[ng], 0, 0, 0);
                }
                __builtin_amdgcn_s_setprio(0);
            }
            // square -> (hi,lo) bf16 via HW cvt_pk -> reduction MFMA into E
            const bf16x8 asgn = (mg == 0) ? asgn0 : asgn1;
#pragma unroll
            for (int ng = 0; ng < 4; ++ng) {
                unsigned wd[4];
#pragma unroll
                for (int r = 0; r < 4; ++r) {
                    const float pr = accr[ng][r] * accr[ng][r]
                                   + acci[ng][r] * acci[ng][r];
                    const unsigned t = cvtpk(pr, pr);        // low16 = bf16(pr)
                    const float hi_f = __builtin_bit_cast(float, t << 16);
                    wd[r] = cvtpk(pr, pr - hi_f);  // low=hi(pr), high=lo(resid)
                }
                const uint4 u4 = {wd[0], wd[1], wd[2], wd[3]};
                const bf16x8 pb = __builtin_bit_cast(bf16x8, u4);
                f32x4 Ein = (ng == 0) ? E0 : (ng == 1) ? E1 : (ng == 2) ? E2 : E3;
                __builtin_amdgcn_s_setprio(1);
                const f32x4 Eout = __builtin_amdgcn_mfma_f32_16x16x32_bf16(
                    asgn, pb, Ein, 0, 0, 0);
                __builtin_amdgcn_s_setprio(0);
                if (ng == 0) E0 = Eout; else if (ng == 1) E1 = Eout;
                else if (ng == 2) E2 = Eout; else E3 = Eout;
            }
        }

        // ---- write expval partials (q = g4*4+r valid for g4<2) ----
        if (g4 < 2) {
#pragma unroll
            for (int ng = 0; ng < 4; ++ng) {
                const f32x4 Ev = (ng == 0) ? E0 : (ng == 1) ? E1 : (ng == 2) ? E2 : E3;
                const int row = ng * 16 + l15;   // batch row
#pragma unroll
                for (int r = 0; r < 4; ++r)
                    ex_part[w][row][g4 * 4 + r] = Ev[r];
            }
        }
        __syncthreads();

        // ---- (d) combine state-col groups (plain sum; signs in A_sgn) ----
        {
            const int row = tid >> 3, q = tid & 7;
            float acc = 0.f;
#pragma unroll
            for (int g = 0; g < 8; ++g) acc += ex_part[g][row][q];
            x_lds[row][q] = acc;
        }
        __syncthreads();
    }

    // output = H[:,4] * float(pi - eps_f32)
    const float MULT = 3.14159253589793f;
    if (tid < 64) out[rowbase + tid] = x_lds[tid][4] * MULT;
}

// ---------------- launcher ------------------------------------------------
extern "C" void kernel_launch(void* const* d_in, const int* in_sizes, int n_in,
                              void* d_out, int out_size, void* d_ws, size_t ws_size,
                              hipStream_t stream) {
    const float* x     = (const float*)d_in[0];   // (32768, 8) fp32
    const float* theta = (const float*)d_in[1];   // (4, 4, 8, 3) fp32
    float* out = (float*)d_out;                   // (32768,) fp32

    char*   ws  = (char*)d_ws;
    ushort* Upr = (ushort*)(ws + 4096);               // 512 KB fragment-major
    ushort* Upi = (ushort*)(ws + 4096 + 524288);      // 512 KB

    ubuild_k<<<256, 256, 0, stream>>>(theta, Upr, Upi);
    vqc_mfma_k<<<512, 512, 0, stream>>>(x, Upr, Upi, out);
}

// Round 16
// 105.727 us; speedup vs baseline: 1.6158x; 1.0018x over previous
//
#include <hip/hip_runtime.h>

// SingleVQC via MFMA. R16 = R15 (48.5us steady, 105.9 bench) + transcendental
// sharing: sin/cos computed ONCE per (row,q) in the (d) phase (and at x-load)
// into hcs[64][16] LDS, instead of 8x redundantly per row in s-build
// (16 quarter-rate trans/thread -> 2). Last VQC writes out[] directly from
// (d) (only q=4 needed). Values bit-identical -> absmax stays 0.046875.

typedef __attribute__((ext_vector_type(8))) short  bf16x8;
typedef __attribute__((ext_vector_type(4))) float  f32x4;

__device__ __forceinline__ ushort f2bf(float f) {
    unsigned u = __builtin_bit_cast(unsigned, f);
    u += 0x7fffu + ((u >> 16) & 1u);          // RNE
    return (ushort)(u >> 16);
}
// HW packed conversion: low16 = bf16(a), high16 = bf16(b), RNE.
__device__ __forceinline__ unsigned cvtpk(float a, float b) {
    unsigned r;
    asm("v_cvt_pk_bf16_f32 %0, %1, %2" : "=v"(r) : "v"(a), "v"(b));
    return r;
}

// ---------------- U-build with in-block gate table (R13, verified) --------
__global__ void ubuild_k(const float* __restrict__ theta,
                         ushort* __restrict__ Upr, ushort* __restrict__ Upi) {
    __shared__ float gts[128 * 8];

    {
        const int idx = threadIdx.x;
        if (idx < 128) {
            float phi = theta[idx * 3 + 0];
            float th  = theta[idx * 3 + 1];
            float om  = theta[idx * 3 + 2];
            float ct = __cosf(0.5f * th),         st = __sinf(0.5f * th);
            float ca = __cosf(0.5f * (phi - om)), sa = __sinf(0.5f * (phi - om));
            float cb = __cosf(0.5f * (phi + om)), sb = __sinf(0.5f * (phi + om));
            float* g = gts + idx * 8;
            g[0] =  cb * ct;  g[1] = -sb * ct;
            g[2] = -ca * st;  g[3] = -sa * st;
            g[4] =  ca * st;  g[5] = -sa * st;
            g[6] =  cb * ct;  g[7] =  sb * ct;
        }
    }
    __syncthreads();

    const int lane = threadIdx.x & 63;
    const int wid  = threadIdx.x >> 6;
    const int wg   = blockIdx.x * 4 + wid;     // 0..1023
    const int v    = wg >> 8;                  // 0..3
    const int j    = wg & 255;                 // basis column = k index

    float ar[4], ai[4];
#pragma unroll
    for (int r = 0; r < 4; ++r) {
        ar[r] = ((lane * 4 + r) == j) ? 1.0f : 0.0f;
        ai[r] = 0.0f;
    }

#pragma unroll
    for (int l = 0; l < 4; ++l) {
        const float* gl = gts + ((v * 4 + l) * 8) * 8;
#pragma unroll
        for (int q = 0; q < 8; ++q) {
            const float* g = gl + q * 8;
            const float g00r = g[0], g00i = g[1], g01r = g[2], g01i = g[3];
            const float g10r = g[4], g10i = g[5], g11r = g[6], g11i = g[7];
            const int b = 7 - q;
            if (b >= 2) {
                const int xm    = 1 << (b - 2);
                const int mybit = (lane >> (b - 2)) & 1;
                const float cAr = mybit ? g11r : g00r;
                const float cAi = mybit ? g11i : g00i;
                const float cBr = mybit ? g10r : g01r;
                const float cBi = mybit ? g10i : g01i;
#pragma unroll
                for (int r = 0; r < 4; ++r) {
                    const float oR = __shfl_xor(ar[r], xm, 64);
                    const float oI = __shfl_xor(ai[r], xm, 64);
                    const float nR = cAr * ar[r] - cAi * ai[r] + cBr * oR - cBi * oI;
                    const float nI = cAr * ai[r] + cAi * ar[r] + cBr * oI + cBi * oR;
                    ar[r] = nR; ai[r] = nI;
                }
            } else {
                const int step = 1 << b;
#pragma unroll
                for (int r0 = 0; r0 < 4; ++r0) {
                    if ((r0 & step) == 0) {
                        const int r1 = r0 | step;
                        const float a0r = ar[r0], a0i = ai[r0];
                        const float a1r = ar[r1], a1i = ai[r1];
                        ar[r0] = g00r * a0r - g00i * a0i + g01r * a1r - g01i * a1i;
                        ai[r0] = g00r * a0i + g00i * a0r + g01r * a1i + g01i * a1r;
                        ar[r1] = g10r * a0r - g10i * a0i + g11r * a1r - g11i * a1i;
                        ai[r1] = g10r * a0i + g10i * a0r + g11r * a1i + g11i * a1r;
                    }
                }
            }
        }
        const int roff = l + 1;
#pragma unroll
        for (int q = 0; q < 8; ++q) {
            const int t  = (q + roff) & 7;
            const int bc = 7 - q;
            const int bt = 7 - t;
            if (bt >= 2) {
                const int xm = 1 << (bt - 2);
                if (bc >= 2) {
                    const int cbit = (lane >> (bc - 2)) & 1;
#pragma unroll
                    for (int r = 0; r < 4; ++r) {
                        const float oR = __shfl_xor(ar[r], xm, 64);
                        const float oI = __shfl_xor(ai[r], xm, 64);
                        ar[r] = cbit ? oR : ar[r];
                        ai[r] = cbit ? oI : ai[r];
                    }
                } else {
#pragma unroll
                    for (int r = 0; r < 4; ++r) {
                        if ((r >> bc) & 1) {
                            ar[r] = __shfl_xor(ar[r], xm, 64);
                            ai[r] = __shfl_xor(ai[r], xm, 64);
                        }
                    }
                }
            } else {
                const int step = 1 << bt;
                if (bc >= 2) {
                    const int cbit = (lane >> (bc - 2)) & 1;
#pragma unroll
                    for (int r0 = 0; r0 < 4; ++r0) {
                        if (((r0 >> bt) & 1) == 0) {
                            const int r1 = r0 | step;
                            const float t0r = cbit ? ar[r1] : ar[r0];
                            const float t0i = cbit ? ai[r1] : ai[r0];
                            const float t1r = cbit ? ar[r0] : ar[r1];
                            const float t1i = cbit ? ai[r0] : ai[r1];
                            ar[r0] = t0r; ai[r0] = t0i;
                            ar[r1] = t1r; ai[r1] = t1i;
                        }
                    }
                } else {
#pragma unroll
                    for (int r0 = 0; r0 < 4; ++r0) {
                        if (((r0 >> bc) & 1) == 1 && ((r0 >> bt) & 1) == 0) {
                            const int r1 = r0 | step;
                            float tr = ar[r0]; ar[r0] = ar[r1]; ar[r1] = tr;
                            float ti = ai[r0]; ai[r0] = ai[r1]; ai[r1] = ti;
                        }
                    }
                }
            }
        }
    }

    // fragment-major store: Upack[v][ks][g4p][col][e], k = j
    const int ks  = j >> 5;
    const int g4p = (j >> 3) & 3;
    const int e   = j & 7;
    ushort* ur = Upr + (size_t)v * 65536 + ((ks * 4 + g4p) * 256) * 8 + e;
    ushort* ui = Upi + (size_t)v * 65536 + ((ks * 4 + g4p) * 256) * 8 + e;
#pragma unroll
    for (int r = 0; r < 4; ++r) {
        const int col = lane * 4 + r;
        ur[col * 8] = f2bf(ar[r]);
        ui[col * 8] = f2bf(ai[r]);
    }
}

// ---------------- fused main kernel (R15 + shared trig) -------------------
// 512 blocks x 512 threads; block owns 64 batch rows through all 4 VQCs.
// Wave w (0..7) owns 32 state-cols, processed as two 16-col passes (mg).
// hcs[row][0..7] = cos(0.5*x_q), hcs[row][8..15] = sin(0.5*x_q), computed
// once per (row,q) by the thread that owns that slot in (d).
__global__ __launch_bounds__(512, 4)
void vqc_mfma_k(const float* __restrict__ xg,
                const ushort* __restrict__ Upr, const ushort* __restrict__ Upi,
                float* __restrict__ out) {
    __shared__ ushort s_lds[64 * 256];        // 32 KB, XOR-swizzled bf16
    __shared__ float  ex_part[8][64][9];      // 18 KB (pad 9)
    __shared__ float  hcs[64][16];            // 4 KB: [row][q]=cos, [row][q+8]=sin

    const int tid  = threadIdx.x;
    const int lane = tid & 63;
    const int w    = tid >> 6;       // state-col group: cols w*32 .. w*32+31
    const int l15  = lane & 15;
    const int g4   = lane >> 4;
    const int rowbase = blockIdx.x * 64;

    // ---- sign-matrix A fragments (built once; 8 VGPRs) ----
    bf16x8 asgn0, asgn1;
    {
        const int q = l15;
#pragma unroll
        for (int mg = 0; mg < 2; ++mg) {
            unsigned wd[4];
#pragma unroll
            for (int p2 = 0; p2 < 4; ++p2) {    // p2 = e>>1
                const int scol = w * 32 + mg * 16 + g4 * 4 + p2;
                ushort uv = 0;
                if (q < 8) uv = ((scol >> (7 - q)) & 1) ? 0xBF80 : 0x3F80;
                wd[p2] = ((unsigned)uv << 16) | uv;   // same sign hi,lo slots
            }
            const uint4 u4 = {wd[0], wd[1], wd[2], wd[3]};
            if (mg == 0) asgn0 = __builtin_bit_cast(bf16x8, u4);
            else         asgn1 = __builtin_bit_cast(bf16x8, u4);
        }
    }

    // initial x: one element per thread (row = tid>>3, q = tid&7) -> sin/cos
    {
        const float xv = xg[(size_t)rowbase * 8 + tid];
        const float h  = 0.5f * xv;
        hcs[tid >> 3][(tid & 7)]     = __cosf(h);
        hcs[tid >> 3][(tid & 7) + 8] = __sinf(h);
    }
    __syncthreads();

    const int srow = tid >> 3;     // s-build: 8 threads per row
    const int sc   = tid & 7;      // 32-amp chunk (amp bits 7,6,5 = q0,1,2)

    for (int v = 0; v < 4; ++v) {
        // ---- (a) build s[row][k] = prod_b f_b(k_b), bf16 swizzled ----
        {
            const float4 c03 = *(const float4*)&hcs[srow][0];
            const float4 c47 = *(const float4*)&hcs[srow][4];
            const float4 s03 = *(const float4*)&hcs[srow][8];
            const float4 s47 = *(const float4*)&hcs[srow][12];
            const float hc[8] = {c03.x, c03.y, c03.z, c03.w,
                                 c47.x, c47.y, c47.z, c47.w};
            const float hs[8] = {s03.x, s03.y, s03.z, s03.w,
                                 s47.x, s47.y, s47.z, s47.w};
            float arr[32];
            arr[0] = (((sc >> 2) & 1) ? hs[0] : hc[0])
                   * (((sc >> 1) & 1) ? hs[1] : hc[1])
                   * (((sc     ) & 1) ? hs[2] : hc[2]);
#define LVL(LEN, FC, FS)                                            \
            _Pragma("unroll")                                       \
            for (int m = (LEN) - 1; m >= 0; --m) {                  \
                arr[2*m+1] = arr[m] * (FS);                         \
                arr[2*m]   = arr[m] * (FC);                         \
            }
            LVL(1,  hc[3], hs[3])   // amp bit4  (q3)
            LVL(2,  hc[4], hs[4])   // bit3      (q4)
            LVL(4,  hc[5], hs[5])   // bit2      (q5)
            LVL(8,  hc[6], hs[6])   // bit1      (q6)
            LVL(16, hc[7], hs[7])   // bit0      (q7)
#undef LVL
            char* sb = (char*)s_lds + srow * 512;
            const int swz = (srow & 7) << 4;
#pragma unroll
            for (int j = 0; j < 4; ++j) {
                uint4 wv;
                wv.x = cvtpk(arr[j*8+0], arr[j*8+1]);
                wv.y = cvtpk(arr[j*8+2], arr[j*8+3]);
                wv.z = cvtpk(arr[j*8+4], arr[j*8+5]);
                wv.w = cvtpk(arr[j*8+6], arr[j*8+7]);
                *(uint4*)(sb + ((sc * 64 + j * 16) ^ swz)) = wv;
            }
        }
        __syncthreads();

        // ---- (b)+(c): per mg (16 cols): GEMM (32 AGPR acc) -> p -> E ----
        const ushort* Ur = Upr + (size_t)v * 65536;
        const ushort* Ui = Upi + (size_t)v * 65536;
        f32x4 E0 = {0.f,0.f,0.f,0.f}, E1 = {0.f,0.f,0.f,0.f};
        f32x4 E2 = {0.f,0.f,0.f,0.f}, E3 = {0.f,0.f,0.f,0.f};

#pragma unroll
        for (int mg = 0; mg < 2; ++mg) {
            f32x4 accr[4], acci[4];
#pragma unroll
            for (int ng = 0; ng < 4; ++ng) {
                accr[ng] = (f32x4){0.f, 0.f, 0.f, 0.f};
                acci[ng] = (f32x4){0.f, 0.f, 0.f, 0.f};
            }
            const int col = w * 32 + mg * 16 + l15;
#pragma unroll
            for (int ks = 0; ks < 8; ++ks) {
                const int boff = ((ks * 4 + g4) * 256 + col) * 8;
                const bf16x8 aur = *(const bf16x8*)(Ur + boff);
                const bf16x8 aui = *(const bf16x8*)(Ui + boff);
                bf16x8 bs[4];
#pragma unroll
                for (int ng = 0; ng < 4; ++ng) {
                    const int row = ng * 16 + l15;
                    const int off = row * 512 +
                        (((ks * 64) + (g4 << 4)) ^ ((row & 7) << 4));
                    bs[ng] = *(const bf16x8*)((const char*)s_lds + off);
                }
                __builtin_amdgcn_s_setprio(1);        // T5: favor MFMA wave
#pragma unroll
                for (int ng = 0; ng < 4; ++ng) {
                    accr[ng] = __builtin_amdgcn_mfma_f32_16x16x32_bf16(
                        aur, bs[ng], accr[ng], 0, 0, 0);
                    acci[ng] = __builtin_amdgcn_mfma_f32_16x16x32_bf16(
                        aui, bs[ng], acci[ng], 0, 0, 0);
                }
                __builtin_amdgcn_s_setprio(0);
            }
            // square -> (hi,lo) bf16 via HW cvt_pk -> reduction MFMA into E
            const bf16x8 asgn = (mg == 0) ? asgn0 : asgn1;
#pragma unroll
            for (int ng = 0; ng < 4; ++ng) {
                unsigned wd[4];
#pragma unroll
                for (int r = 0; r < 4; ++r) {
                    const float pr = accr[ng][r] * accr[ng][r]
                                   + acci[ng][r] * acci[ng][r];
                    const unsigned t = cvtpk(pr, pr);        // low16 = bf16(pr)
                    const float hi_f = __builtin_bit_cast(float, t << 16);
                    wd[r] = cvtpk(pr, pr - hi_f);  // low=hi(pr), high=lo(resid)
                }
                const uint4 u4 = {wd[0], wd[1], wd[2], wd[3]};
                const bf16x8 pb = __builtin_bit_cast(bf16x8, u4);
                f32x4 Ein = (ng == 0) ? E0 : (ng == 1) ? E1 : (ng == 2) ? E2 : E3;
                __builtin_amdgcn_s_setprio(1);
                const f32x4 Eout = __builtin_amdgcn_mfma_f32_16x16x32_bf16(
                    asgn, pb, Ein, 0, 0, 0);
                __builtin_amdgcn_s_setprio(0);
                if (ng == 0) E0 = Eout; else if (ng == 1) E1 = Eout;
                else if (ng == 2) E2 = Eout; else E3 = Eout;
            }
        }

        // ---- write expval partials (q = g4*4+r valid for g4<2) ----
        if (g4 < 2) {
#pragma unroll
            for (int ng = 0; ng < 4; ++ng) {
                const f32x4 Ev = (ng == 0) ? E0 : (ng == 1) ? E1 : (ng == 2) ? E2 : E3;
                const int row = ng * 16 + l15;   // batch row
#pragma unroll
                for (int r = 0; r < 4; ++r)
                    ex_part[w][row][g4 * 4 + r] = Ev[r];
            }
        }
        __syncthreads();

        // ---- (d) combine col-groups; publish sin/cos (or final out) ----
        {
            const int row = tid >> 3, q = tid & 7;
            float acc = 0.f;
#pragma unroll
            for (int g = 0; g < 8; ++g) acc += ex_part[g][row][q];
            if (v < 3) {
                const float h = 0.5f * acc;
                hcs[row][q]     = __cosf(h);
                hcs[row][q + 8] = __sinf(h);
            } else if (q == 4) {
                const float MULT = 3.14159253589793f;   // float(pi - eps_f32)
                out[rowbase + row] = acc * MULT;
            }
        }
        __syncthreads();
    }
}

// ---------------- launcher ------------------------------------------------
extern "C" void kernel_launch(void* const* d_in, const int* in_sizes, int n_in,
                              void* d_out, int out_size, void* d_ws, size_t ws_size,
                              hipStream_t stream) {
    const float* x     = (const float*)d_in[0];   // (32768, 8) fp32
    const float* theta = (const float*)d_in[1];   // (4, 4, 8, 3) fp32
    float* out = (float*)d_out;                   // (32768,) fp32

    char*   ws  = (char*)d_ws;
    ushort* Upr = (ushort*)(ws + 4096);               // 512 KB fragment-major
    ushort* Upi = (ushort*)(ws + 4096 + 524288);      // 512 KB

    ubuild_k<<<256, 256, 0, stream>>>(theta, Upr, Upi);
    vqc_mfma_k<<<512, 512, 0, stream>>>(x, Upr, Upi, out);
}